// Round 4
// baseline (349.676 us; speedup 1.0000x reference)
//
#include <hip/hip_runtime.h>

typedef unsigned char  u8;
typedef unsigned short u16;
typedef unsigned int   u32;
typedef unsigned long long u64;
typedef __attribute__((ext_vector_type(8))) short bf16x8;
typedef __attribute__((ext_vector_type(4))) float f32x4;

#define NOBS 128
#define NN   1280
#define NH   256
#define NO   80
#define TT   5
#define RR   16          // batch rows per block
#define NTHR 512         // 8 waves/block, 2 col-tiles per wave
#define BP1  88          // layer1 bits LDS pitch (u16)
#define BP2  20          // layer2/3 bits pitch (u16)

// ws layout (u16 units), stage-contiguous: [kc][ks][sel][rows][32], rows
// XOR-swizzled within. W1s [20][2][3][256][32] @0 ;
// W2s [4][2][3][256][32] @983040 ; Wos [4][2][3][128][32] @1179648 (pad128).
// flags: 512 u32 at u16-offset WS_TOTAL — flags[b]==MAGIC means block b's
// grid-stride split share was completed by a prior kernel launch.
#define W1TOT   983040
#define W2S_OFF 983040
#define WOS_OFF 1179648
#define WS_TOTAL 1277952
#define NBLK 512
#define GRID_THREADS (NBLK * NTHR)
#define MAGIC 0x5AFE5A1Du

#define VMW2()  asm volatile("s_waitcnt vmcnt(2)" ::: "memory")
#define VMW0()  asm volatile("s_waitcnt vmcnt(0)" ::: "memory")
#define LGKM0() asm volatile("s_waitcnt lgkmcnt(0)" ::: "memory")
#define FENCE() asm volatile("" ::: "memory")

__device__ __forceinline__ float bf2f(u16 u) {
  union { u32 i; float f; } x; x.i = ((u32)u) << 16; return x.f;
}
__device__ __forceinline__ u16 f2bf(float f) {
  union { float f; u32 i; } x; x.f = f;
  u32 i = x.i + 0x7FFFu + ((x.i >> 16) & 1u);   // RNE
  return (u16)(i >> 16);
}

// 3-way bf16 split: w ~= hi + mid + lo, residual <= 2^-27 |w|.
__device__ __forceinline__ u16 split3(float w, int sel) {
  u16 hi = f2bf(w);
  if (sel == 0) return hi;
  float r1 = __fsub_rn(w, bf2f(hi));        // exact
  u16 mid = f2bf(r1);
  if (sel == 1) return mid;
  float r2 = __fsub_rn(r1, bf2f(mid));      // exact
  return f2bf(r2);
}

// Inline near-correctly-rounded f32 exp via f64 degree-11 Taylor.
__device__ __forceinline__ float exp_cr(float arg) {
  double xa = (double)arg;
  double nd = __builtin_rint(xa * 1.4426950408889634074);
  double r  = fma(nd, -6.93147180369123816490e-01, xa);
  r         = fma(nd, -1.90821492927058770002e-10, r);
  double p = 2.50521083854417187751e-08;
  p = fma(p, r, 2.75573192239858906526e-07);
  p = fma(p, r, 2.75573192239858906526e-06);
  p = fma(p, r, 2.48015873015873015873e-05);
  p = fma(p, r, 1.98412698412698412698e-04);
  p = fma(p, r, 1.38888888888888888889e-03);
  p = fma(p, r, 8.33333333333333333333e-03);
  p = fma(p, r, 4.16666666666666666667e-02);
  p = fma(p, r, 1.66666666666666666667e-01);
  p = fma(p, r, 0.5);
  p = fma(p, r, 1.0);
  p = fma(p, r, 1.0);
  int n = (int)nd;
  union { u64 u; double d; } s;
  s.u = ((u64)(u32)(n + 1023)) << 52;
  return (n < -150) ? 0.f : (float)(s.d * p);
}

// One grid-stride item of the weight split (identical arithmetic/layout to
// the original prep kernel — bit-identical ws contents). Swizzle:
// sub-fragment s (8 u16) of row j stored at position s ^ ((j>>1)&3).
__device__ __forceinline__ void split_item(
    int i, const float* __restrict__ W1, const float* __restrict__ W2,
    const float* __restrict__ Wo, u16* __restrict__ ws)
{
  if (i < W1TOT) {                          // W1 [256][1280]
    int kc = i / 49152, r = i - kc * 49152;
    int ks = r / 24576, r2 = r - ks * 24576;
    int sel = r2 / 8192, r3 = r2 & 8191;
    int j = r3 >> 5, kkpos = r3 & 31;
    int kk = ((kkpos >> 3) ^ ((j >> 1) & 3)) * 8 + (kkpos & 7);
    ws[i] = split3(W1[j * 1280 + kc * 64 + ks * 32 + kk], sel);
  } else if (i < WOS_OFF) {                 // W2 [256][256]
    int i2 = i - W2S_OFF;
    int kc = i2 / 49152, r = i2 - kc * 49152;
    int ks = r / 24576, r2 = r - ks * 24576;
    int sel = r2 / 8192, r3 = r2 & 8191;
    int j = r3 >> 5, kkpos = r3 & 31;
    int kk = ((kkpos >> 3) ^ ((j >> 1) & 3)) * 8 + (kkpos & 7);
    ws[i] = split3(W2[j * 256 + kc * 64 + ks * 32 + kk], sel);
  } else {                                  // Wo [80][256] padded to 128 rows
    int i3 = i - WOS_OFF;
    int kc = i3 / 24576, r = i3 - kc * 24576;
    int ks = r / 12288, r2 = r - ks * 12288;
    int sel = r2 / 4096, r3 = r2 & 4095;
    int j = r3 >> 5, kkpos = r3 & 31;
    int kk = ((kkpos >> 3) ^ ((j >> 1) & 3)) * 8 + (kkpos & 7);
    float w = (j < NO) ? Wo[j * 256 + kc * 64 + ks * 32 + kk] : 0.f;
    ws[i] = split3(w, sel);
  }
}

// DMA this wave's 2KB stage slice (1024 u16) into LDS: 2 instructions,
// wave-uniform LDS base + implicit lane*16.
__device__ __forceinline__ void dma2(const u16* __restrict__ src, u16* dst, int lane) {
  __builtin_amdgcn_global_load_lds((const u32*)(src + lane * 8), (u32*)dst, 16, 0, 0);
  __builtin_amdgcn_global_load_lds((const u32*)(src + 512 + lane * 8),
                                   (u32*)(dst + 512), 16, 0, 0);
}

// Shared A-fragment build: expand 8 spike bits x 5 t into bf16 0/1 fragments.
__device__ __forceinline__ void build_afr(
    const u16* lbits, int bpitch, int kc, int ks, int m16, int sh, bf16x8 afr[TT])
{
  #pragma unroll
  for (int t = 0; t < TT; ++t) {
    u32 bwv = *(const u32*)(lbits + (t * RR + m16) * bpitch + kc * 4 + ks * 2);
    u32 b = (bwv >> sh) & 0xFFu;
    union { u32 u[4]; bf16x8 v; } x;
    #pragma unroll
    for (int i = 0; i < 4; ++i)
      x.u[i] = ((((b >> (2 * i)) & 3u) * 0x8001u) & 0x00010001u) * 0x3F80u;
    afr[t] = x.v;
  }
}

// FAST path: barrier-free wave-private staged GEMM, register-prefetch
// pipelined (R2, unchanged). Reads pre-split ws via global_load_lds,
// triple-buffered, per-wave vmcnt pacing. Per-column accumulation order
// kc:(ks0:hi,mid,lo),(ks1:hi,mid,lo).
__device__ __forceinline__ void gemm_wp(
    const u16* lbits, int bpitch,
    const u16* __restrict__ wsbase, int nkc, int selblk,
    u16* mybuf, int wv, int lane, f32x4 acc[2][TT])
{
  const int m16 = lane & 15, q = lane >> 4;
  const int swz = (q ^ ((m16 >> 1) & 3)) * 8;
  const int lro0 = m16 * 32 + swz;           // local row m16
  const int lro1 = lro0 + 512;               // local row m16+16
  const int sh = q * 8;
  const int nst = nkc * 6;
  const u16* slice = wsbase + wv * 1024;

  dma2(slice, mybuf, lane);                  // st 0 -> buf 0
  dma2(slice + selblk, mybuf + 1024, lane);  // st 1 -> buf 1
  FENCE();
  VMW2();                                    // st0 landed (st1 still in flight)
  bf16x8 cur0 = *(const bf16x8*)(mybuf + lro0);
  bf16x8 cur1 = *(const bf16x8*)(mybuf + lro1);
  FENCE();

  int st = 0;
  for (int kcks = 0; kcks < nkc * 2; ++kcks) {
    const int kc = kcks >> 1, ks = kcks & 1;
    bf16x8 afr[TT];
    build_afr(lbits, bpitch, kc, ks, m16, sh, afr);
    #pragma unroll
    for (int sel = 0; sel < 3; ++sel, ++st) {
      // Issue st+2's DMA first: target buf (sel+2)%3 was prefetch-read at
      // body st-1 (lgkm-waited before st's MFMAs below) — WAR-safe.
      if (st + 2 < nst)
        dma2(slice + (st + 2) * selblk, mybuf + ((sel + 2) % 3) * 1024, lane);
      FENCE();
      #pragma unroll
      for (int t = 0; t < TT; ++t)
        acc[0][t] = __builtin_amdgcn_mfma_f32_16x16x32_bf16(afr[t], cur0, acc[0][t], 0, 0, 0);
      #pragma unroll
      for (int t = 0; t < TT; ++t)
        acc[1][t] = __builtin_amdgcn_mfma_f32_16x16x32_bf16(afr[t], cur1, acc[1][t], 0, 0, 0);
      if (st + 1 < nst) {                    // prefetch next stage's B-frags
        if (st + 2 < nst) { VMW2(); } else { VMW0(); }
        const u16* nb = mybuf + ((sel + 1) % 3) * 1024;
        cur0 = *(const bf16x8*)(nb + lro0);
        cur1 = *(const bf16x8*)(nb + lro1);
      }
      FENCE();
    }
  }
}

// SLOW path (first launch after workspace poison only): reconstruct each
// stage's 2KB slice from the RAW f32 weights in-registers (split3 ->
// ds_write_b128), bytes bit-identical to what the split would have placed
// in ws. No block ever READS ws on this path — correctness never depends
// on intra-kernel cross-XCD visibility (the R3 failure mode). Serial
// staging; runs once per poison.
__device__ __forceinline__ void gemm_slow(
    const u16* lbits, int bpitch,
    const float* __restrict__ W, int ld, int jmax, int nkc,
    u16* mybuf, int wv, int lane, f32x4 acc[2][TT])
{
  const int m16 = lane & 15, q = lane >> 4;
  const int swz = (q ^ ((m16 >> 1) & 3)) * 8;
  const int lro0 = m16 * 32 + swz;
  const int lro1 = lro0 + 512;
  const int sh = q * 8;
  for (int kcks = 0; kcks < nkc * 2; ++kcks) {
    const int kc = kcks >> 1, ks = kcks & 1;
    bf16x8 afr[TT];
    build_afr(lbits, bpitch, kc, ks, m16, sh, afr);
    #pragma unroll
    for (int sel = 0; sel < 3; ++sel) {
      const int colbase = kc * 64 + ks * 32;
      #pragma unroll
      for (int h = 0; h < 2; ++h) {
        // slice u16 index u = h*512 + lane*8 + e  ->  row j, col kk:
        // j = wv*32 + h*16 + lane/4 ; kkpos = (lane&3)*8+e ;
        // kk = ((lane&3) ^ ((j>>1)&3))*8 + e   (the prep swizzle, inverted)
        const int j = wv * 32 + h * 16 + (lane >> 2);
        const int kk0 = ((lane & 3) ^ ((j >> 1) & 3)) << 3;
        union { u16 u[8]; uint4 qv; } o;
        if (j < jmax) {
          const float* src = W + j * ld + colbase + kk0;   // 32B-aligned
          const float4 w0 = *(const float4*)(src);
          const float4 w1 = *(const float4*)(src + 4);
          o.u[0] = split3(w0.x, sel); o.u[1] = split3(w0.y, sel);
          o.u[2] = split3(w0.z, sel); o.u[3] = split3(w0.w, sel);
          o.u[4] = split3(w1.x, sel); o.u[5] = split3(w1.y, sel);
          o.u[6] = split3(w1.z, sel); o.u[7] = split3(w1.w, sel);
        } else {
          #pragma unroll
          for (int e = 0; e < 8; ++e) o.u[e] = 0;   // pad rows (split3(0)=0)
        }
        *(uint4*)(mybuf + h * 512 + lane * 8) = o.qv;
      }
      LGKM0();
      __builtin_amdgcn_sched_barrier(0);
      const bf16x8 bf0 = *(const bf16x8*)(mybuf + lro0);
      const bf16x8 bf1 = *(const bf16x8*)(mybuf + lro1);
      #pragma unroll
      for (int t = 0; t < TT; ++t)
        acc[0][t] = __builtin_amdgcn_mfma_f32_16x16x32_bf16(afr[t], bf0, acc[0][t], 0, 0, 0);
      #pragma unroll
      for (int t = 0; t < TT; ++t)
        acc[1][t] = __builtin_amdgcn_mfma_f32_16x16x32_bf16(afr[t], bf1, acc[1][t], 0, 0, 0);
      LGKM0();
      __builtin_amdgcn_sched_barrier(0);
    }
  }
}

// LIF recurrence over t; emit spike bits via ballot. 2 col-tiles per wave.
__device__ __forceinline__ void recur_spikes2(
    f32x4 acc[2][TT], const float* __restrict__ bias,
    int lane, int wv, u16* sbits, int spitch)
{
  const int q = lane >> 4, m16 = lane & 15;
  #pragma unroll
  for (int i = 0; i < 2; ++i) {
    int ct = wv * 2 + i;
    int j = ct * 16 + m16;
    float bj = bias[j];
    #pragma unroll
    for (int rg = 0; rg < 4; ++rg) {
      float c = 0.f, v = 0.f, sprev = 0.f;
      #pragma unroll
      for (int t = 0; t < TT; ++t) {
        float u = acc[i][t][rg];
        c = __fadd_rn(__fadd_rn(__fmul_rn(c, 0.5f), u), bj);       // (c*0.5 + u) + b
        float vd = __fmul_rn(v, 0.75f);
        v = __fadd_rn((sprev > 0.5f) ? 0.f : vd, c);               // v*0.75*(1-s) + c
        bool sp = v > 0.5f;
        u64 mask = __ballot(sp);
        if (m16 == 0) {
          int row = q * 4 + rg;
          sbits[(t * RR + row) * spitch + ct] = (u16)(mask >> (q * 16));
        }
        sprev = sp ? 1.f : 0.f;
      }
    }
  }
}

// Single kernel, single launch. Per block: [flags check] -> [encoder] ->
// [3-layer SNN: fast (ws DMA) or slow (on-the-fly split) GEMM] -> [decoder]
// -> [if slow: write grid-stride ws share + own flag for future launches].
__global__ __launch_bounds__(NTHR, 4) void snn_one(
    const float* __restrict__ W1, const float* __restrict__ W2,
    const float* __restrict__ Wo,
    const float* __restrict__ obs, const float* __restrict__ enc_mean,
    const float* __restrict__ enc_std,
    const float* __restrict__ b1, const float* __restrict__ b2, const float* __restrict__ bo,
    const float* __restrict__ dec_w, const float* __restrict__ dec_b, const float* __restrict__ log_std,
    u16* __restrict__ wsW, float* __restrict__ out, int Btot)
{
  __shared__ __align__(16) u16 smem[37376];          // 74,752 B -> 2 blocks/CU
  __shared__ u32 okw[8];
  u16* bufs = smem;                                  // [8 waves][3][1024]
  u16* encb = smem + 24576;                          // [5t*16r][BP1] = 7040
  u16* s1b  = encb + 7040;                           // [5t*16r][BP2] = 1600
  u16* s2b  = s1b + 1600;                            // 1600
  float* soacc = (float*)(s2b + 1600);               // [16][80] f32 (own region)

  const int tid  = threadIdx.x;
  const int lane = tid & 63;
  const int wv   = tid >> 6;          // 0..7
  const int r0   = blockIdx.x * RR;
  u16* mybuf = bufs + wv * 3072;

  // ---------- ws-validity check: all 512 block flags must be MAGIC ---------
  {
    u32 fv = ((const u32*)(wsW + WS_TOTAL))[tid];    // 512 thr <-> 512 flags
    u64 bal = __ballot(fv == MAGIC);
    if (lane == 0) okw[wv] = (bal == ~0ull) ? 1u : 0u;
  }

  // ---------- fused population encoder: 16 rows x 1280 cols -> bit-planes --
  // 2560 half-items of 8 exps, exactly 5 per thread; bit-identical per-k
  // arithmetic to the original encoder.
  for (int h = tid; h < RR * 160; h += NTHR) {
    int r = h / 160, rem = h - r * 160;
    int w = rem >> 1, hi = rem & 1;
    const float* obsrow = obs + (r0 + r) * NOBS;
    u32 bits[TT] = {0, 0, 0, 0, 0};
    #pragma unroll
    for (int e = 0; e < 8; ++e) {
      int k = w * 16 + hi * 8 + e;
      int f = k / 10;
      float x  = obsrow[f];
      float m  = enc_mean[k];
      float sd = enc_std[k];
      float d  = __fsub_rn(x, m);
      float arg = __fdiv_rn(__fmul_rn(-0.5f, __fmul_rn(d, d)), __fmul_rn(sd, sd));
      float a = exp_cr(arg);
      float v = 0.f;
      #pragma unroll
      for (int t = 0; t < TT; ++t) {
        v = __fadd_rn(v, a);
        if (v > 0.999f) { bits[t] |= (1u << e); v = __fsub_rn(v, 0.999f); }
      }
    }
    u8* eb = (u8*)encb;
    #pragma unroll
    for (int t = 0; t < TT; ++t)
      eb[((t * RR + r) * BP1 + w) * 2 + hi] = (u8)bits[t];
  }
  __syncthreads();                                   // encb + okw ready
  const bool fastok =
      (okw[0] & okw[1] & okw[2] & okw[3] & okw[4] & okw[5] & okw[6] & okw[7]) != 0;

  f32x4 acc[2][TT];
  const f32x4 zero4 = {0.f, 0.f, 0.f, 0.f};
#define ZERO_ACC() { _Pragma("unroll") for (int i = 0; i < 2; ++i) \
                     _Pragma("unroll") for (int t = 0; t < TT; ++t) acc[i][t] = zero4; }

  // ---------- layer 1: [80 x 1280] @ [1280 x 256] (3-way split fused) ------
  ZERO_ACC();
  if (fastok) gemm_wp(encb, BP1, wsW, 20, 8192, mybuf, wv, lane, acc);
  else        gemm_slow(encb, BP1, W1, 1280, 256, 20, mybuf, wv, lane, acc);
  recur_spikes2(acc, b1, lane, wv, s1b, BP2);
  __syncthreads();

  // ---------- layer 2: [80 x 256] @ [256 x 256] ----------------------------
  ZERO_ACC();
  if (fastok) gemm_wp(s1b, BP2, wsW + W2S_OFF, 4, 8192, mybuf, wv, lane, acc);
  else        gemm_slow(s1b, BP2, W2, 256, 256, 4, mybuf, wv, lane, acc);
  recur_spikes2(acc, b2, lane, wv, s2b, BP2);
  __syncthreads();

  // ---------- layer 3: [80 x 256] @ [256 x 80(pad)] — waves 0..2 -----------
  if (wv < 3) {
    ZERO_ACC();
    if (fastok) gemm_wp(s2b, BP2, wsW + WOS_OFF, 4, 4096, mybuf, wv, lane, acc);
    else        gemm_slow(s2b, BP2, Wo, 256, NO, 4, mybuf, wv, lane, acc);
    const int q = lane >> 4, m16 = lane & 15;
    #pragma unroll
    for (int i = 0; i < 2; ++i) {
      int j = (wv * 2 + i) * 16 + m16;
      bool valid = j < NO;
      float bj = valid ? bo[j] : 0.f;
      #pragma unroll
      for (int rg = 0; rg < 4; ++rg) {
        float c = 0.f, v = 0.f, sprev = 0.f;
        int cnt = 0;
        #pragma unroll
        for (int t = 0; t < TT; ++t) {
          float u = acc[i][t][rg];
          c = __fadd_rn(__fadd_rn(__fmul_rn(c, 0.5f), u), bj);
          float vd = __fmul_rn(v, 0.75f);
          v = __fadd_rn((sprev > 0.5f) ? 0.f : vd, c);
          bool sp = v > 0.5f;
          cnt += sp ? 1 : 0;
          sprev = sp ? 1.f : 0.f;
        }
        if (valid) soacc[(q * 4 + rg) * NO + j] = __fdiv_rn((float)cnt, 5.0f);
      }
    }
  }
  __syncthreads();

  // ---------- decoder: grouped dot + ELU -----------------------------------
  if (tid < RR * 8) {
    int r = tid >> 3, a = tid & 7;
    float s = 0.f;
    const float* so = soacc + r * NO + a * 10;
    #pragma unroll
    for (int p = 0; p < 10; ++p)
      s = __fadd_rn(s, __fmul_rn(so[p], dec_w[a * 10 + p]));
    s = __fadd_rn(s, dec_b[a]);
    float mu = (s > 0.f) ? s : expm1f(s);
    out[(r0 + r) * 8 + a] = mu;
  }
  if (blockIdx.x == 0 && tid < 8) {
    out[Btot * 8 + tid] = expf(log_std[tid]);
  }

  // ---------- slow path only: publish split ws + flag for future launches --
  // Visibility to the NEXT launch is guaranteed by the kernel-boundary cache
  // flush (stream-ordered); nobody reads these within this launch.
  if (!fastok) {
    const int gtid = blockIdx.x * NTHR + tid;
    #pragma unroll
    for (int p = 0; p < 5; ++p) {
      int i = p * GRID_THREADS + gtid;
      if (i < WS_TOTAL) split_item(i, W1, W2, Wo, wsW);
    }
    __threadfence();
    __syncthreads();
    if (tid == 0) ((u32*)(wsW + WS_TOTAL))[blockIdx.x] = MAGIC;
  }
}

extern "C" void kernel_launch(void* const* d_in, const int* in_sizes, int n_in,
                              void* d_out, int out_size, void* d_ws, size_t ws_size,
                              hipStream_t stream) {
  const float* obs      = (const float*)d_in[0];
  const float* enc_mean = (const float*)d_in[1];
  const float* enc_std  = (const float*)d_in[2];
  const float* W1       = (const float*)d_in[3];
  const float* b1       = (const float*)d_in[4];
  const float* W2       = (const float*)d_in[5];
  const float* b2       = (const float*)d_in[6];
  const float* Wo       = (const float*)d_in[7];
  const float* bo       = (const float*)d_in[8];
  const float* dec_w    = (const float*)d_in[9];
  const float* dec_b    = (const float*)d_in[10];
  const float* log_std  = (const float*)d_in[11];
  u16*   ws  = (u16*)d_ws;
  float* out = (float*)d_out;
  int B = in_sizes[0] / NOBS;   // 8192

  hipLaunchKernelGGL(snn_one, dim3(B / RR), dim3(NTHR), 0, stream,
                     W1, W2, Wo, obs, enc_mean, enc_std,
                     b1, b2, bo, dec_w, dec_b, log_std, ws, out, B);
}

// Round 6
// 167.919 us; speedup vs baseline: 2.0824x; 2.0824x over previous
//
#include <hip/hip_runtime.h>

typedef unsigned char  u8;
typedef unsigned short u16;
typedef unsigned int   u32;
typedef unsigned long long u64;
typedef __attribute__((ext_vector_type(8))) short bf16x8;
typedef __attribute__((ext_vector_type(4))) float f32x4;

#define NOBS 128
#define NN   1280
#define NH   256
#define NO   80
#define TT   5
#define RR   16          // batch rows per block
#define NTHR 512         // 8 waves/block, 2 col-tiles per wave
#define BP1  88          // layer1 bits LDS pitch (u16)
#define BP2  20          // layer2/3 bits pitch (u16)

// ws layout (u16 units), stage-contiguous: [kc][ks][sel][rows][32], rows
// XOR-swizzled within (sub-fragment s of row j stored at s ^ ((j>>1)&3)).
// W1s [20][2][3][256][32] @0 ; W2s [4][2][3][256][32] @983040 ;
// Wos [4][2][3][128][32] @1179648 (pad128)
#define W1TOT   983040
#define W2S_OFF 983040
#define WOS_OFF 1179648
#define WS_TOTAL 1277952

#define PREP_BLOCKS 208           // 53248 threads, 24 ws items each

#define VMW2()  asm volatile("s_waitcnt vmcnt(2)" ::: "memory")
#define VMW0()  asm volatile("s_waitcnt vmcnt(0)" ::: "memory")
#define FENCE() asm volatile("" ::: "memory")

__device__ __forceinline__ float bf2f(u16 u) {
  union { u32 i; float f; } x; x.i = ((u32)u) << 16; return x.f;
}
__device__ __forceinline__ u16 f2bf(float f) {
  union { float f; u32 i; } x; x.f = f;
  u32 i = x.i + 0x7FFFu + ((x.i >> 16) & 1u);   // RNE
  return (u16)(i >> 16);
}

// Inline near-correctly-rounded f32 exp via f64 degree-11 Taylor.
__device__ __forceinline__ float exp_cr(float arg) {
  double xa = (double)arg;
  double nd = __builtin_rint(xa * 1.4426950408889634074);
  double r  = fma(nd, -6.93147180369123816490e-01, xa);
  r         = fma(nd, -1.90821492927058770002e-10, r);
  double p = 2.50521083854417187751e-08;
  p = fma(p, r, 2.75573192239858906526e-07);
  p = fma(p, r, 2.75573192239858906526e-06);
  p = fma(p, r, 2.48015873015873015873e-05);
  p = fma(p, r, 1.98412698412698412698e-04);
  p = fma(p, r, 1.38888888888888888889e-03);
  p = fma(p, r, 8.33333333333333333333e-03);
  p = fma(p, r, 4.16666666666666666667e-02);
  p = fma(p, r, 1.66666666666666666667e-01);
  p = fma(p, r, 0.5);
  p = fma(p, r, 1.0);
  p = fma(p, r, 1.0);
  int n = (int)nd;
  union { u64 u; double d; } s;
  s.u = ((u64)(u32)(n + 1023)) << 52;
  return (n < -150) ? 0.f : (float)(s.d * p);
}

// Weight-split prep, vectorized (R5, hand-verified vs scalar mapping): each
// thread owns 8 contiguous source cols of one row and emits all 3 sel
// planes — 2 float4 loads, 8 hi/mid/lo splits, 3 coalesced 16B stores.
// Same split arithmetic and same swizzled storage positions as the original
// scalar prep -> bit-identical ws.
__global__ __launch_bounds__(256) void prep_w(
    const float* __restrict__ W1, const float* __restrict__ W2,
    const float* __restrict__ Wo, u16* __restrict__ ws)
{
  const int T = blockIdx.x * 256 + threadIdx.x;     // < 53248 exactly
  const float* src;
  int dstb, selstep;
  bool pad = false;
  if (T < 40960) {                                  // W1 [256][1280]
    int kcks = T >> 10, r = T & 1023;
    int kc = kcks >> 1, ks = kcks & 1, j = r >> 2, kgrp = r & 3;
    int kk0 = (kgrp ^ ((j >> 1) & 3)) << 3;
    src = W1 + j * 1280 + kc * 64 + ks * 32 + kk0;
    dstb = kc * 49152 + ks * 24576 + j * 32 + kgrp * 8;
    selstep = 8192;
  } else if (T < 49152) {                           // W2 [256][256]
    int T2 = T - 40960;
    int kcks = T2 >> 10, r = T2 & 1023;
    int kc = kcks >> 1, ks = kcks & 1, j = r >> 2, kgrp = r & 3;
    int kk0 = (kgrp ^ ((j >> 1) & 3)) << 3;
    src = W2 + j * 256 + kc * 64 + ks * 32 + kk0;
    dstb = W2S_OFF + kc * 49152 + ks * 24576 + j * 32 + kgrp * 8;
    selstep = 8192;
  } else {                                          // Wo [80][256] pad to 128
    int T3 = T - 49152;
    int kcks = T3 >> 9, r = T3 & 511;
    int kc = kcks >> 1, ks = kcks & 1, j = r >> 2, kgrp = r & 3;
    int kk0 = (kgrp ^ ((j >> 1) & 3)) << 3;
    src = Wo + j * 256 + kc * 64 + ks * 32 + kk0;
    dstb = WOS_OFF + kc * 24576 + ks * 12288 + j * 32 + kgrp * 8;
    selstep = 4096;
    pad = (j >= NO);
  }
  float w[8];
  if (!pad) {
    float4 w0 = *(const float4*)src;          // 32B-aligned
    float4 w1 = *(const float4*)(src + 4);
    w[0] = w0.x; w[1] = w0.y; w[2] = w0.z; w[3] = w0.w;
    w[4] = w1.x; w[5] = w1.y; w[6] = w1.z; w[7] = w1.w;
  } else {
    #pragma unroll
    for (int e = 0; e < 8; ++e) w[e] = 0.f;
  }
  union { u16 u[8]; uint4 q; } hi, mid, lo;
  #pragma unroll
  for (int e = 0; e < 8; ++e) {
    u16 h = f2bf(w[e]);
    float r1 = __fsub_rn(w[e], bf2f(h));      // exact
    u16 m = f2bf(r1);
    float r2 = __fsub_rn(r1, bf2f(m));        // exact
    hi.u[e] = h; mid.u[e] = m; lo.u[e] = f2bf(r2);
  }
  *(uint4*)(ws + dstb)               = hi.q;
  *(uint4*)(ws + dstb + selstep)     = mid.q;
  *(uint4*)(ws + dstb + 2 * selstep) = lo.q;
}

// DMA this wave's 2KB stage slice (1024 u16) into LDS: 2 instructions,
// both with EXPLICIT addresses and offset=0 (R6: the R5 imm-offset variant
// was wrong — the global_load_lds imm offset applies to BOTH the global and
// the LDS address, double-offsetting the LDS dest by 1KB). lane_src already
// includes this lane's +lane*8; LDS dst is wave-uniform base + lane*16.
__device__ __forceinline__ void dma2(const u16* __restrict__ lane_src, u16* dst) {
  __builtin_amdgcn_global_load_lds((const u32*)lane_src, (u32*)dst, 16, 0, 0);
  __builtin_amdgcn_global_load_lds((const u32*)(lane_src + 512),
                                   (u32*)(dst + 512), 16, 0, 0);
}

// Barrier-free wave-private staged GEMM, register-prefetch pipelined (R2),
// with LUT-based A-fragment expansion (R5): the 4-way select per u32 (2
// spike bits -> packed bf16 pair) is a 16-entry x 8B LDS LUT read. Entry n
// lives on banks 2n/2n+1 (all 16 disjoint), same-entry reads broadcast ->
// conflict-free for any lane pattern. Values bit-identical to the ALU form.
// Wait rule preserves the R16 race fix: before prefetching st+1's B-frags
// wait VMW2 if st+2's DMA is in flight, else VMW0. Per-column accumulation
// order kc:(ks0:hi,mid,lo),(ks1:hi,mid,lo) — bit-identical to all rounds.
__device__ __forceinline__ void gemm_wp(
    const u16* lbits, int bpitch,
    const u16* __restrict__ wsbase, int nkc, int selblk,
    u16* mybuf, const u64* __restrict__ lut,
    int wv, int lane, f32x4 acc[2][TT])
{
  const int m16 = lane & 15, q = lane >> 4;
  const int swz = (q ^ ((m16 >> 1) & 3)) * 8;
  const int lro0 = m16 * 32 + swz;           // local row m16
  const int lro1 = lro0 + 512;               // local row m16+16
  const int sh = q * 8;
  const int nst = nkc * 6;
  const u16* lsrc = wsbase + wv * 1024 + lane * 8;   // per-lane src, st 0

  dma2(lsrc, mybuf);                         // st 0 -> buf 0
  dma2(lsrc + selblk, mybuf + 1024);         // st 1 -> buf 1
  const u16* nsrc = lsrc + 2 * selblk;       // next DMA source (st 2)
  FENCE();
  VMW2();                                    // st0 landed (st1 still in flight)
  bf16x8 cur0 = *(const bf16x8*)(mybuf + lro0);
  bf16x8 cur1 = *(const bf16x8*)(mybuf + lro1);
  FENCE();

  int st = 0;
  for (int kcks = 0; kcks < nkc * 2; ++kcks) {
    const int kc = kcks >> 1, ks = kcks & 1;
    bf16x8 afr[TT];
    #pragma unroll
    for (int t = 0; t < TT; ++t) {
      u32 bwv = *(const u32*)(lbits + (t * RR + m16) * bpitch + kc * 4 + ks * 2);
      u32 b = (bwv >> sh) & 0xFFu;
      union { u64 d[2]; bf16x8 v; } x;
      x.d[0] = lut[b & 15u];
      x.d[1] = lut[b >> 4];
      afr[t] = x.v;
    }
    #pragma unroll
    for (int sel = 0; sel < 3; ++sel, ++st) {
      // Issue st+2's DMA first: target buf (sel+2)%3 was prefetch-read at
      // body st-1 (lgkm-waited before st's MFMAs below) — WAR-safe.
      if (st + 2 < nst) {
        dma2(nsrc, mybuf + ((sel + 2) % 3) * 1024);
        nsrc += selblk;
      }
      FENCE();
      #pragma unroll
      for (int t = 0; t < TT; ++t)
        acc[0][t] = __builtin_amdgcn_mfma_f32_16x16x32_bf16(afr[t], cur0, acc[0][t], 0, 0, 0);
      #pragma unroll
      for (int t = 0; t < TT; ++t)
        acc[1][t] = __builtin_amdgcn_mfma_f32_16x16x32_bf16(afr[t], cur1, acc[1][t], 0, 0, 0);
      if (st + 1 < nst) {                    // prefetch next stage's B-frags
        if (st + 2 < nst) { VMW2(); } else { VMW0(); }
        const u16* nb = mybuf + ((sel + 1) % 3) * 1024;
        cur0 = *(const bf16x8*)(nb + lro0);
        cur1 = *(const bf16x8*)(nb + lro1);
      }
      FENCE();
    }
  }
}

// LIF recurrence over t; emit spike bits via ballot. 2 col-tiles per wave.
__device__ __forceinline__ void recur_spikes2(
    f32x4 acc[2][TT], const float* __restrict__ bias,
    int lane, int wv, u16* sbits, int spitch)
{
  const int q = lane >> 4, m16 = lane & 15;
  #pragma unroll
  for (int i = 0; i < 2; ++i) {
    int ct = wv * 2 + i;
    int j = ct * 16 + m16;
    float bj = bias[j];
    #pragma unroll
    for (int rg = 0; rg < 4; ++rg) {
      float c = 0.f, v = 0.f, sprev = 0.f;
      #pragma unroll
      for (int t = 0; t < TT; ++t) {
        float u = acc[i][t][rg];
        c = __fadd_rn(__fadd_rn(__fmul_rn(c, 0.5f), u), bj);       // (c*0.5 + u) + b
        float vd = __fmul_rn(v, 0.75f);
        v = __fadd_rn((sprev > 0.5f) ? 0.f : vd, c);               // v*0.75*(1-s) + c
        bool sp = v > 0.5f;
        u64 mask = __ballot(sp);
        if (m16 == 0) {
          int row = q * 4 + rg;
          sbits[(t * RR + row) * spitch + ct] = (u16)(mask >> (q * 16));
        }
        sprev = sp ? 1.f : 0.f;
      }
    }
  }
}

__global__ __launch_bounds__(NTHR, 4) void snn_main(
    const float* __restrict__ obs, const float* __restrict__ enc_mean,
    const float* __restrict__ enc_std,
    const float* __restrict__ b1, const float* __restrict__ b2, const float* __restrict__ bo,
    const float* __restrict__ dec_w, const float* __restrict__ dec_b, const float* __restrict__ log_std,
    const u16* __restrict__ wsW, float* __restrict__ out, int Btot)
{
  __shared__ __align__(16) u16 smem[37440];          // 74,880 B -> 2 blocks/CU
  u16* bufs = smem;                                  // [8 waves][3][1024]
  u16* encb = smem + 24576;                          // [5t*16r][BP1] = 7040
  u16* s1b  = encb + 7040;                           // [5t*16r][BP2] = 1600
  u16* s2b  = s1b + 1600;                            // 1600
  float* soacc = (float*)(s2b + 1600);               // [16][80] f32 (own region)
  u64* lutp = (u64*)(smem + 37376);                  // 16 x 8B nibble LUT

  const int tid  = threadIdx.x;
  const int lane = tid & 63;
  const int wv   = tid >> 6;          // 0..7
  const int r0   = blockIdx.x * RR;
  u16* mybuf = bufs + wv * 3072;

  // ---------- nibble->bf16x4 LUT (bit-identical to the ALU expansion) ------
  if (tid < 16) {
    u32 lo32 = (((tid & 3u) * 0x8001u) & 0x10001u) * 0x3F80u;
    u32 hi32 = ((((tid >> 2) & 3u) * 0x8001u) & 0x10001u) * 0x3F80u;
    lutp[tid] = (u64)lo32 | ((u64)hi32 << 32);
  }

  // ---------- fused population encoder: 16 rows x 1280 cols -> bit-planes --
  // 2560 half-items of 8 exps, exactly 5 per thread; bit-identical per-k
  // arithmetic to the original encoder.
  for (int h = tid; h < RR * 160; h += NTHR) {
    int r = h / 160, rem = h - r * 160;
    int w = rem >> 1, hi = rem & 1;
    const float* obsrow = obs + (r0 + r) * NOBS;
    u32 bits[TT] = {0, 0, 0, 0, 0};
    #pragma unroll
    for (int e = 0; e < 8; ++e) {
      int k = w * 16 + hi * 8 + e;
      int f = k / 10;
      float x  = obsrow[f];
      float m  = enc_mean[k];
      float sd = enc_std[k];
      float d  = __fsub_rn(x, m);
      float arg = __fdiv_rn(__fmul_rn(-0.5f, __fmul_rn(d, d)), __fmul_rn(sd, sd));
      float a = exp_cr(arg);
      float v = 0.f;
      #pragma unroll
      for (int t = 0; t < TT; ++t) {
        v = __fadd_rn(v, a);
        if (v > 0.999f) { bits[t] |= (1u << e); v = __fsub_rn(v, 0.999f); }
      }
    }
    u8* eb = (u8*)encb;
    #pragma unroll
    for (int t = 0; t < TT; ++t)
      eb[((t * RR + r) * BP1 + w) * 2 + hi] = (u8)bits[t];
  }
  __syncthreads();                                   // encb + LUT ready

  f32x4 acc[2][TT];
  const f32x4 zero4 = {0.f, 0.f, 0.f, 0.f};
#define ZERO_ACC() { _Pragma("unroll") for (int i = 0; i < 2; ++i) \
                     _Pragma("unroll") for (int t = 0; t < TT; ++t) acc[i][t] = zero4; }

  // ---------- layer 1: [80 x 1280] @ [1280 x 256] (3-way split fused) ------
  ZERO_ACC();
  gemm_wp(encb, BP1, wsW, 20, 8192, mybuf, lutp, wv, lane, acc);
  recur_spikes2(acc, b1, lane, wv, s1b, BP2);
  __syncthreads();

  // ---------- layer 2: [80 x 256] @ [256 x 256] ----------------------------
  ZERO_ACC();
  gemm_wp(s1b, BP2, wsW + W2S_OFF, 4, 8192, mybuf, lutp, wv, lane, acc);
  recur_spikes2(acc, b2, lane, wv, s2b, BP2);
  __syncthreads();

  // ---------- layer 3: [80 x 256] @ [256 x 80(pad)] — waves 0..2 -----------
  if (wv < 3) {
    ZERO_ACC();
    gemm_wp(s2b, BP2, wsW + WOS_OFF, 4, 4096, mybuf, lutp, wv, lane, acc);
    const int q = lane >> 4, m16 = lane & 15;
    #pragma unroll
    for (int i = 0; i < 2; ++i) {
      int j = (wv * 2 + i) * 16 + m16;
      bool valid = j < NO;
      float bj = valid ? bo[j] : 0.f;
      #pragma unroll
      for (int rg = 0; rg < 4; ++rg) {
        float c = 0.f, v = 0.f, sprev = 0.f;
        int cnt = 0;
        #pragma unroll
        for (int t = 0; t < TT; ++t) {
          float u = acc[i][t][rg];
          c = __fadd_rn(__fadd_rn(__fmul_rn(c, 0.5f), u), bj);
          float vd = __fmul_rn(v, 0.75f);
          v = __fadd_rn((sprev > 0.5f) ? 0.f : vd, c);
          bool sp = v > 0.5f;
          cnt += sp ? 1 : 0;
          sprev = sp ? 1.f : 0.f;
        }
        if (valid) soacc[(q * 4 + rg) * NO + j] = __fdiv_rn((float)cnt, 5.0f);
      }
    }
  }
  __syncthreads();

  // ---------- decoder: grouped dot + ELU -----------------------------------
  if (tid < RR * 8) {
    int r = tid >> 3, a = tid & 7;
    float s = 0.f;
    const float* so = soacc + r * NO + a * 10;
    #pragma unroll
    for (int p = 0; p < 10; ++p)
      s = __fadd_rn(s, __fmul_rn(so[p], dec_w[a * 10 + p]));
    s = __fadd_rn(s, dec_b[a]);
    float mu = (s > 0.f) ? s : expm1f(s);
    out[(r0 + r) * 8 + a] = mu;
  }
  if (blockIdx.x == 0 && tid < 8) {
    out[Btot * 8 + tid] = expf(log_std[tid]);
  }
}

extern "C" void kernel_launch(void* const* d_in, const int* in_sizes, int n_in,
                              void* d_out, int out_size, void* d_ws, size_t ws_size,
                              hipStream_t stream) {
  const float* obs      = (const float*)d_in[0];
  const float* enc_mean = (const float*)d_in[1];
  const float* enc_std  = (const float*)d_in[2];
  const float* W1       = (const float*)d_in[3];
  const float* b1       = (const float*)d_in[4];
  const float* W2       = (const float*)d_in[5];
  const float* b2       = (const float*)d_in[6];
  const float* Wo       = (const float*)d_in[7];
  const float* bo       = (const float*)d_in[8];
  const float* dec_w    = (const float*)d_in[9];
  const float* dec_b    = (const float*)d_in[10];
  const float* log_std  = (const float*)d_in[11];
  u16*   ws  = (u16*)d_ws;
  float* out = (float*)d_out;
  int B = in_sizes[0] / NOBS;   // 8192

  hipLaunchKernelGGL(prep_w, dim3(PREP_BLOCKS), dim3(256), 0, stream,
                     W1, W2, Wo, ws);
  hipLaunchKernelGGL(snn_main, dim3(B / RR), dim3(NTHR), 0, stream,
                     obs, enc_mean, enc_std, b1, b2, bo, dec_w, dec_b, log_std,
                     ws, out, B);
}